// Round 9
// baseline (91.210 us; speedup 1.0000x reference)
//
#include <hip/hip_runtime.h>
#include <math.h>

namespace {

constexpr int SEQ    = 8;
constexpr int WCHUNK = 64 * SEQ;   // 512 elements = one wave's chunk

struct V3 { float x, y, z; };
struct Q4 { float x, y, z, w; };
struct St { Q4 q; V3 s; V3 p; float T; float pad; }; // 48 B

__device__ __forceinline__ Q4 qmul(const Q4 a, const Q4 b) {
  Q4 r;
  r.x = a.w*b.x + b.w*a.x + a.y*b.z - a.z*b.y;
  r.y = a.w*b.y + b.w*a.y + a.z*b.x - a.x*b.z;
  r.z = a.w*b.z + b.w*a.z + a.x*b.y - a.y*b.x;
  r.w = a.w*b.w - a.x*b.x - a.y*b.y - a.z*b.z;
  return r;
}

__device__ __forceinline__ V3 qrot(const Q4 q, const V3 v) {
  float tx = q.y*v.z - q.z*v.y + q.w*v.x;
  float ty = q.z*v.x - q.x*v.z + q.w*v.y;
  float tz = q.x*v.y - q.y*v.x + q.w*v.z;
  V3 r;
  r.x = v.x + 2.0f*(q.y*tz - q.z*ty);
  r.y = v.y + 2.0f*(q.z*tx - q.x*tz);
  r.z = v.z + 2.0f*(q.x*ty - q.y*tx);
  return r;
}

__device__ __forceinline__ St combine(const St a, const St b) {
  St r;
  r.q = qmul(a.q, b.q);
  V3 rs = qrot(a.q, b.s);
  r.s.x = a.s.x + rs.x;
  r.s.y = a.s.y + rs.y;
  r.s.z = a.s.z + rs.z;
  V3 rp = qrot(a.q, b.p);
  r.p.x = a.p.x + a.s.x*b.T + rp.x;
  r.p.y = a.p.y + a.s.y*b.T + rp.y;
  r.p.z = a.p.z + a.s.z*b.T + rp.z;
  r.T = a.T + b.T;
  r.pad = 0.0f;
  return r;
}

__device__ __forceinline__ St identity_st() {
  St r;
  r.q = {0.0f, 0.0f, 0.0f, 1.0f};
  r.s = {0.0f, 0.0f, 0.0f};
  r.p = {0.0f, 0.0f, 0.0f};
  r.T = 0.0f; r.pad = 0.0f;
  return r;
}

// θ = |gyro*dt| ≤ ~0.02 here: 2-term Taylor in θ² is fp32-exact. No libm.
__device__ __forceinline__ St elem_state(float dt, V3 w, V3 ac, Q4 gt) {
  float px = w.x*dt, py = w.y*dt, pz = w.z*dt;
  float t2 = px*px + py*py + pz*pz;                        // θ²
  float k  = 0.5f + t2*(-1.0f/48.0f  + t2*(1.0f/3840.0f)); // sin(θ/2)/θ
  float cw = 1.0f + t2*(-0.125f      + t2*(1.0f/384.0f));  // cos(θ/2)
  Q4 dr = { px*k, py*k, pz*k, cw };
  Q4 gi = { -gt.x, -gt.y, -gt.z, gt.w };
  V3 g  = { 0.0f, 0.0f, 9.81007f };
  V3 gr = qrot(gi, g);
  V3 a  = { ac.x - gr.x, ac.y - gr.y, ac.z - gr.z };
  V3 ra = qrot(dr, a);
  St e;
  e.q = dr;
  e.s.x = ra.x*dt; e.s.y = ra.y*dt; e.s.z = ra.z*dt;
  float h = 0.5f*dt;
  e.p.x = e.s.x*h; e.p.y = e.s.y*h; e.p.z = e.s.z*h;
  e.T = dt; e.pad = 0.0f;
  return e;
}

// reconstruct element state from compressed 7 floats (q.w = sqrt(1-|qv|^2):
// valid since |qv| <= ~0.01 and w > 0; validated in R7 phase B, absmax 32)
__device__ __forceinline__ St recon(float qx, float qy, float qz,
                                    float sx, float sy, float sz, float dt) {
  St e;
  e.q = { qx, qy, qz, sqrtf(fmaxf(1.0f - qx*qx - qy*qy - qz*qz, 0.0f)) };
  e.s = { sx, sy, sz };
  float h = 0.5f*dt;
  e.p = { sx*h, sy*h, sz*h };
  e.T = dt; e.pad = 0.0f;
  return e;
}

__device__ __forceinline__ St shfl_up_st(const St& v, int d) {
  St r;
  r.q.x = __shfl_up(v.q.x, d); r.q.y = __shfl_up(v.q.y, d);
  r.q.z = __shfl_up(v.q.z, d); r.q.w = __shfl_up(v.q.w, d);
  r.s.x = __shfl_up(v.s.x, d); r.s.y = __shfl_up(v.s.y, d);
  r.s.z = __shfl_up(v.s.z, d);
  r.p.x = __shfl_up(v.p.x, d); r.p.y = __shfl_up(v.p.y, d);
  r.p.z = __shfl_up(v.p.z, d);
  r.T   = __shfl_up(v.T, d);   r.pad = 0.0f;
  return r;
}

__device__ __forceinline__ St shfl_down_st(const St& v, int d) {
  St r;
  r.q.x = __shfl_down(v.q.x, d); r.q.y = __shfl_down(v.q.y, d);
  r.q.z = __shfl_down(v.q.z, d); r.q.w = __shfl_down(v.q.w, d);
  r.s.x = __shfl_down(v.s.x, d); r.s.y = __shfl_down(v.s.y, d);
  r.s.z = __shfl_down(v.s.z, d);
  r.p.x = __shfl_down(v.p.x, d); r.p.y = __shfl_down(v.p.y, d);
  r.p.z = __shfl_down(v.p.z, d);
  r.T   = __shfl_down(v.T, d);   r.pad = 0.0f;
  return r;
}

// Kernel 1: per-chunk aggregates. 4 INDEPENDENT waves per 256-thr block
// (no LDS, no barriers); each wave owns one 512-elem chunk.
// combine is NON-COMMUTATIVE; the shfl_down halving reduce is
// order-preserving (lane i merges [i,i+d) with [i+d,i+2d)).
__global__ __launch_bounds__(256) void k_agg(
    const float* __restrict__ dtp, const float* __restrict__ gyp,
    const float* __restrict__ acp, const float* __restrict__ gtp,
    St* __restrict__ aggs, int F, int cpb)
{
  const int tid  = threadIdx.x;
  const int lane = tid & 63;
  const int cid  = blockIdx.x * 4 + (tid >> 6);
  const int b = cid / cpb, c = cid - b*cpb;
  const size_t gi = (size_t)b*F + (size_t)c*WCHUNK + (size_t)lane*SEQ;

  St run;
  {
    float dtv[SEQ], gy[SEQ*3], acv[SEQ*3], gq[SEQ*4];
    #pragma unroll
    for (int j = 0; j < SEQ/4; ++j)   ((float4*)dtv)[j] = ((const float4*)(dtp + gi))[j];
    #pragma unroll
    for (int j = 0; j < SEQ*3/4; ++j) ((float4*)gy)[j]  = ((const float4*)(gyp + gi*3))[j];
    #pragma unroll
    for (int j = 0; j < SEQ*3/4; ++j) ((float4*)acv)[j] = ((const float4*)(acp + gi*3))[j];
    #pragma unroll
    for (int j = 0; j < SEQ; ++j)     ((float4*)gq)[j]  = ((const float4*)(gtp + gi*4))[j];
    #pragma unroll
    for (int i = 0; i < SEQ; ++i) {
      St e = elem_state(dtv[i],
                 {gy[3*i], gy[3*i+1], gy[3*i+2]},
                 {acv[3*i], acv[3*i+1], acv[3*i+2]},
                 {gq[4*i], gq[4*i+1], gq[4*i+2], gq[4*i+3]});
      if (i == 0) run = e; else run = combine(run, e);
    }
  }
  #pragma unroll
  for (int d = 1; d < 64; d <<= 1) run = combine(run, shfl_down_st(run, d));
  if (lane == 0) aggs[cid] = run;
}

// Kernel 2: chunk prefixes, one wave per batch row (cpb <= 64).
// lane l: inclusive wave-scan of aggs[row], exclusive = shfl_up(1), seed it.
__global__ __launch_bounds__(64) void k_pref(
    const St* __restrict__ aggs, const float* __restrict__ irp,
    float* __restrict__ prefb, int cpb)
{
  const int b = blockIdx.x;
  const int lane = threadIdx.x & 63;

  St A = identity_st();
  if (lane < cpb) A = aggs[(size_t)b*cpb + lane];
  #pragma unroll
  for (int d = 1; d < 64; d <<= 1) {
    St o = shfl_up_st(A, d);
    if (lane >= d) A = combine(o, A);
  }
  St seed = identity_st();
  seed.q = { irp[b*4+0], irp[b*4+1], irp[b*4+2], irp[b*4+3] };
  St ex = shfl_up_st(A, 1);
  St P = (lane == 0) ? seed : combine(seed, ex);
  if (lane < cpb) {
    float4* pp = (float4*)(prefb + ((size_t)b*cpb + lane)*12);
    pp[0] = make_float4(P.q.x, P.q.y, P.q.z, P.q.w);
    pp[1] = make_float4(P.s.x, P.s.y, P.s.z, P.p.x);
    pp[2] = make_float4(P.p.y, P.p.z, P.T, 0.0f);
  }
}

// Kernel 3: emit. 4 INDEPENDENT waves per 256-thr block, no LDS/barriers.
// Wave loads its precomputed 48 B prefix (uniform broadcast), scans its own
// 512-elem chunk in registers (states compressed to 7 floats/elem), emits.
__global__ __launch_bounds__(256) void k_emit(
    const float* __restrict__ dtp, const float* __restrict__ gyp,
    const float* __restrict__ acp, const float* __restrict__ gtp,
    const float* __restrict__ prefb,
    const float* __restrict__ ivp, const float* __restrict__ ipp,
    float* __restrict__ out, int F, int cpb, int B)
{
  const int tid  = threadIdx.x;
  const int lane = tid & 63;
  const int cid  = blockIdx.x * 4 + (tid >> 6);
  const int b = cid / cpb, c = cid - b*cpb;
  const size_t gi = (size_t)b*F + (size_t)c*WCHUNK + (size_t)lane*SEQ;

  // uniform per-wave prefix load (issued first; latency hides under build)
  St P;
  {
    const float4* pp = (const float4*)(prefb + (size_t)cid*12);
    float4 a = pp[0], bb = pp[1], cc = pp[2];
    P.q = {a.x, a.y, a.z, a.w};
    P.s = {bb.x, bb.y, bb.z};
    P.p = {bb.w, cc.x, cc.y};
    P.T = cc.z; P.pad = 0.0f;
  }

  // build compressed element states + thread-local aggregate
  float cq[SEQ*3], cs[SEQ*3], cdt[SEQ];
  St run;
  {
    float dtv[SEQ], gy[SEQ*3], acv[SEQ*3], gq[SEQ*4];
    #pragma unroll
    for (int j = 0; j < SEQ/4; ++j)   ((float4*)dtv)[j] = ((const float4*)(dtp + gi))[j];
    #pragma unroll
    for (int j = 0; j < SEQ*3/4; ++j) ((float4*)gy)[j]  = ((const float4*)(gyp + gi*3))[j];
    #pragma unroll
    for (int j = 0; j < SEQ*3/4; ++j) ((float4*)acv)[j] = ((const float4*)(acp + gi*3))[j];
    #pragma unroll
    for (int j = 0; j < SEQ; ++j)     ((float4*)gq)[j]  = ((const float4*)(gtp + gi*4))[j];
    #pragma unroll
    for (int i = 0; i < SEQ; ++i) {
      St e = elem_state(dtv[i],
                 {gy[3*i], gy[3*i+1], gy[3*i+2]},
                 {acv[3*i], acv[3*i+1], acv[3*i+2]},
                 {gq[4*i], gq[4*i+1], gq[4*i+2], gq[4*i+3]});
      cq[3*i] = e.q.x; cq[3*i+1] = e.q.y; cq[3*i+2] = e.q.z;
      cs[3*i] = e.s.x; cs[3*i+1] = e.s.y; cs[3*i+2] = e.s.z;
      cdt[i]  = e.T;
      if (i == 0) run = e; else run = combine(run, e);
    }
  }

  // wave inclusive scan of thread aggregates (order-correct)
  St incl = run;
  #pragma unroll
  for (int d = 1; d < 64; d <<= 1) {
    St o = shfl_up_st(incl, d);
    if (lane >= d) incl = combine(o, incl);
  }
  {
    St ex = shfl_up_st(incl, 1);
    if (lane > 0) P = combine(P, ex);
  }

  V3 iv = { ivp[b*3+0], ivp[b*3+1], ivp[b*3+2] };
  V3 ip = { ipp[b*3+0], ipp[b*3+1], ipp[b*3+2] };

  const size_t BF = (size_t)B * (size_t)F;
  float4* rot4 = (float4*)out;
  float*  velp = out + BF*4;
  float*  posp = out + BF*7;

  St acc = P;
  float velb[SEQ*3], posb[SEQ*3];
  #pragma unroll
  for (int i = 0; i < SEQ; ++i) {
    St e = recon(cq[3*i], cq[3*i+1], cq[3*i+2],
                 cs[3*i], cs[3*i+1], cs[3*i+2], cdt[i]);
    acc = combine(acc, e);
    rot4[gi + i] = make_float4(acc.q.x, acc.q.y, acc.q.z, acc.q.w);
    velb[3*i+0] = iv.x + acc.s.x;
    velb[3*i+1] = iv.y + acc.s.y;
    velb[3*i+2] = iv.z + acc.s.z;
    posb[3*i+0] = ip.x + iv.x*acc.T + acc.p.x;
    posb[3*i+1] = ip.y + iv.y*acc.T + acc.p.y;
    posb[3*i+2] = ip.z + iv.z*acc.T + acc.p.z;
  }
  #pragma unroll
  for (int j = 0; j < SEQ*3/4; ++j) {
    ((float4*)(velp + gi*3))[j] = ((float4*)velb)[j];
    ((float4*)(posp + gi*3))[j] = ((float4*)posb)[j];
  }
}

} // namespace

extern "C" void kernel_launch(void* const* d_in, const int* in_sizes, int n_in,
                              void* d_out, int out_size, void* d_ws, size_t ws_size,
                              hipStream_t stream)
{
  (void)n_in; (void)out_size; (void)ws_size;

  const float* dtp = (const float*)d_in[0];
  const float* gyp = (const float*)d_in[1];
  const float* acp = (const float*)d_in[2];
  const float* gtp = (const float*)d_in[3];
  const float* irp = (const float*)d_in[4];
  const float* ivp = (const float*)d_in[5];
  const float* ipp = (const float*)d_in[6];
  float* out = (float*)d_out;

  const int B   = in_sizes[4] / 4;    // init_rot has B*4 elements
  const int F   = in_sizes[0] / B;    // dt has B*F elements
  const int cpb = F / WCHUNK;         // 64 for F=32768 (must be <= 64)
  const int nchunk = B * cpb;         // 4096

  St*    aggs  = (St*)d_ws;
  float* prefb = (float*)((char*)d_ws + (size_t)nchunk * sizeof(St));

  k_agg <<<nchunk/4, 256, 0, stream>>>(dtp, gyp, acp, gtp, aggs, F, cpb);
  k_pref<<<B,         64, 0, stream>>>(aggs, irp, prefb, cpb);
  k_emit<<<nchunk/4, 256, 0, stream>>>(dtp, gyp, acp, gtp, prefb, ivp, ipp,
                                       out, F, cpb, B);
}

// Round 10
// 76.271 us; speedup vs baseline: 1.1959x; 1.1959x over previous
//
#include <hip/hip_runtime.h>
#include <math.h>

namespace {

constexpr int SEQ    = 4;
constexpr int WCHUNK = 64 * SEQ;   // 256 elements = one wave's chunk

struct V3 { float x, y, z; };
struct Q4 { float x, y, z, w; };
struct St { Q4 q; V3 s; V3 p; float T; float pad; }; // 48 B

__device__ __forceinline__ Q4 qmul(const Q4 a, const Q4 b) {
  Q4 r;
  r.x = a.w*b.x + b.w*a.x + a.y*b.z - a.z*b.y;
  r.y = a.w*b.y + b.w*a.y + a.z*b.x - a.x*b.z;
  r.z = a.w*b.z + b.w*a.z + a.x*b.y - a.y*b.x;
  r.w = a.w*b.w - a.x*b.x - a.y*b.y - a.z*b.z;
  return r;
}

__device__ __forceinline__ V3 qrot(const Q4 q, const V3 v) {
  float tx = q.y*v.z - q.z*v.y + q.w*v.x;
  float ty = q.z*v.x - q.x*v.z + q.w*v.y;
  float tz = q.x*v.y - q.y*v.x + q.w*v.z;
  V3 r;
  r.x = v.x + 2.0f*(q.y*tz - q.z*ty);
  r.y = v.y + 2.0f*(q.z*tx - q.x*tz);
  r.z = v.z + 2.0f*(q.x*ty - q.y*tx);
  return r;
}

__device__ __forceinline__ St combine(const St a, const St b) {
  St r;
  r.q = qmul(a.q, b.q);
  V3 rs = qrot(a.q, b.s);
  r.s.x = a.s.x + rs.x;
  r.s.y = a.s.y + rs.y;
  r.s.z = a.s.z + rs.z;
  V3 rp = qrot(a.q, b.p);
  r.p.x = a.p.x + a.s.x*b.T + rp.x;
  r.p.y = a.p.y + a.s.y*b.T + rp.y;
  r.p.z = a.p.z + a.s.z*b.T + rp.z;
  r.T = a.T + b.T;
  r.pad = 0.0f;
  return r;
}

__device__ __forceinline__ St identity_st() {
  St r;
  r.q = {0.0f, 0.0f, 0.0f, 1.0f};
  r.s = {0.0f, 0.0f, 0.0f};
  r.p = {0.0f, 0.0f, 0.0f};
  r.T = 0.0f; r.pad = 0.0f;
  return r;
}

// θ = |gyro*dt| ≤ ~0.02 here: 2-term Taylor in θ² is fp32-exact. No libm.
__device__ __forceinline__ St elem_state(float dt, V3 w, V3 ac, Q4 gt) {
  float px = w.x*dt, py = w.y*dt, pz = w.z*dt;
  float t2 = px*px + py*py + pz*pz;                        // θ²
  float k  = 0.5f + t2*(-1.0f/48.0f  + t2*(1.0f/3840.0f)); // sin(θ/2)/θ
  float cw = 1.0f + t2*(-0.125f      + t2*(1.0f/384.0f));  // cos(θ/2)
  Q4 dr = { px*k, py*k, pz*k, cw };
  Q4 gi = { -gt.x, -gt.y, -gt.z, gt.w };
  V3 g  = { 0.0f, 0.0f, 9.81007f };
  V3 gr = qrot(gi, g);
  V3 a  = { ac.x - gr.x, ac.y - gr.y, ac.z - gr.z };
  V3 ra = qrot(dr, a);
  St e;
  e.q = dr;
  e.s.x = ra.x*dt; e.s.y = ra.y*dt; e.s.z = ra.z*dt;
  float h = 0.5f*dt;
  e.p.x = e.s.x*h; e.p.y = e.s.y*h; e.p.z = e.s.z*h;
  e.T = dt; e.pad = 0.0f;
  return e;
}

// reconstruct single-element state from 7 floats (q.w = sqrt(1-|qv|^2):
// valid since |qv| <= ~0.01, w > 0; validated R7/R9, absmax 16)
__device__ __forceinline__ St recon(float qx, float qy, float qz,
                                    float sx, float sy, float sz, float dt) {
  St e;
  e.q = { qx, qy, qz, sqrtf(fmaxf(1.0f - qx*qx - qy*qy - qz*qz, 0.0f)) };
  e.s = { sx, sy, sz };
  float h = 0.5f*dt;
  e.p = { sx*h, sy*h, sz*h };
  e.T = dt; e.pad = 0.0f;
  return e;
}

__device__ __forceinline__ St shfl_up_st(const St& v, int d) {
  St r;
  r.q.x = __shfl_up(v.q.x, d); r.q.y = __shfl_up(v.q.y, d);
  r.q.z = __shfl_up(v.q.z, d); r.q.w = __shfl_up(v.q.w, d);
  r.s.x = __shfl_up(v.s.x, d); r.s.y = __shfl_up(v.s.y, d);
  r.s.z = __shfl_up(v.s.z, d);
  r.p.x = __shfl_up(v.p.x, d); r.p.y = __shfl_up(v.p.y, d);
  r.p.z = __shfl_up(v.p.z, d);
  r.T   = __shfl_up(v.T, d);   r.pad = 0.0f;
  return r;
}

__device__ __forceinline__ St shfl_down_st(const St& v, int d) {
  St r;
  r.q.x = __shfl_down(v.q.x, d); r.q.y = __shfl_down(v.q.y, d);
  r.q.z = __shfl_down(v.q.z, d); r.q.w = __shfl_down(v.q.w, d);
  r.s.x = __shfl_down(v.s.x, d); r.s.y = __shfl_down(v.s.y, d);
  r.s.z = __shfl_down(v.s.z, d);
  r.p.x = __shfl_down(v.p.x, d); r.p.y = __shfl_down(v.p.y, d);
  r.p.z = __shfl_down(v.p.z, d);
  r.T   = __shfl_down(v.T, d);   r.pad = 0.0f;
  return r;
}

__device__ __forceinline__ St bcast_st(const St& v, int src) {
  St r;
  r.q.x = __shfl(v.q.x, src); r.q.y = __shfl(v.q.y, src);
  r.q.z = __shfl(v.q.z, src); r.q.w = __shfl(v.q.w, src);
  r.s.x = __shfl(v.s.x, src); r.s.y = __shfl(v.s.y, src);
  r.s.z = __shfl(v.s.z, src);
  r.p.x = __shfl(v.p.x, src); r.p.y = __shfl(v.p.y, src);
  r.p.z = __shfl(v.p.z, src);
  r.T   = __shfl(v.T, src);   r.pad = 0.0f;
  return r;
}

// Kernel 1: per-chunk aggregates. 4 INDEPENDENT waves per 256-thr block
// (no LDS, no barriers); each wave owns one 256-elem chunk.
// combine is NON-COMMUTATIVE; the shfl_down halving reduce is
// order-preserving (lane i merges [i,i+d) with [i+d,i+2d)).
__global__ __launch_bounds__(256) void k_agg(
    const float* __restrict__ dtp, const float* __restrict__ gyp,
    const float* __restrict__ acp, const float* __restrict__ gtp,
    St* __restrict__ aggs, int F, int cpb)
{
  const int tid  = threadIdx.x;
  const int lane = tid & 63;
  const int cid  = blockIdx.x * 4 + (tid >> 6);
  const int b = cid / cpb, c = cid - b*cpb;
  const size_t gi = (size_t)b*F + (size_t)c*WCHUNK + (size_t)lane*SEQ;

  St run;
  {
    float dtv[SEQ], gy[SEQ*3], acv[SEQ*3], gq[SEQ*4];
    *((float4*)dtv) = *(const float4*)(dtp + gi);
    #pragma unroll
    for (int j = 0; j < 3; ++j) ((float4*)gy)[j]  = ((const float4*)(gyp + gi*3))[j];
    #pragma unroll
    for (int j = 0; j < 3; ++j) ((float4*)acv)[j] = ((const float4*)(acp + gi*3))[j];
    #pragma unroll
    for (int j = 0; j < 4; ++j) ((float4*)gq)[j]  = ((const float4*)(gtp + gi*4))[j];
    #pragma unroll
    for (int i = 0; i < SEQ; ++i) {
      St e = elem_state(dtv[i],
                 {gy[3*i], gy[3*i+1], gy[3*i+2]},
                 {acv[3*i], acv[3*i+1], acv[3*i+2]},
                 {gq[4*i], gq[4*i+1], gq[4*i+2], gq[4*i+3]});
      if (i == 0) run = e; else run = combine(run, e);
    }
  }
  #pragma unroll
  for (int d = 1; d < 64; d <<= 1) run = combine(run, shfl_down_st(run, d));
  if (lane == 0) aggs[cid] = run;
}

// Kernel 2: exclusive chunk prefixes. One wave per batch row; cpb scanned in
// 64-wide windows with a running carry (cpb = 128 -> 2 windows).
// P(c) = seed(b) ∘ agg[0..c);  carry_{w+1} = carry_w ∘ incl_w[63].
__global__ __launch_bounds__(64) void k_pref(
    const St* __restrict__ aggs, const float* __restrict__ irp,
    float* __restrict__ prefb, int cpb)
{
  const int b = blockIdx.x;
  const int lane = threadIdx.x & 63;

  St carry = identity_st();
  carry.q = { irp[b*4+0], irp[b*4+1], irp[b*4+2], irp[b*4+3] };

  const int nw = (cpb + 63) >> 6;
  for (int w = 0; w < nw; ++w) {
    const int idx = (w << 6) + lane;
    St A = identity_st();
    if (idx < cpb) A = aggs[(size_t)b*cpb + idx];
    #pragma unroll
    for (int d = 1; d < 64; d <<= 1) {
      St o = shfl_up_st(A, d);
      if (lane >= d) A = combine(o, A);
    }
    St ex = shfl_up_st(A, 1);
    St P = (lane == 0) ? carry : combine(carry, ex);
    if (idx < cpb) {
      float4* pp = (float4*)(prefb + ((size_t)b*cpb + idx)*12);
      pp[0] = make_float4(P.q.x, P.q.y, P.q.z, P.q.w);
      pp[1] = make_float4(P.s.x, P.s.y, P.s.z, P.p.x);
      pp[2] = make_float4(P.p.y, P.p.z, P.T, 0.0f);
    }
    carry = combine(carry, bcast_st(A, 63));
  }
}

// Kernel 3: emit. 4 INDEPENDENT waves per 256-thr block, no LDS/barriers.
// Wave's 48 B exclusive prefix is a broadcast load (issued first); element
// states kept compressed (7 floats each); wave shuffle scan; serial emit.
__global__ __launch_bounds__(256) void k_emit(
    const float* __restrict__ dtp, const float* __restrict__ gyp,
    const float* __restrict__ acp, const float* __restrict__ gtp,
    const float* __restrict__ prefb,
    const float* __restrict__ ivp, const float* __restrict__ ipp,
    float* __restrict__ out, int F, int cpb, int B)
{
  const int tid  = threadIdx.x;
  const int lane = tid & 63;
  const int cid  = blockIdx.x * 4 + (tid >> 6);
  const int b = cid / cpb, c = cid - b*cpb;
  const size_t gi = (size_t)b*F + (size_t)c*WCHUNK + (size_t)lane*SEQ;

  // per-wave uniform prefix load (hardware-broadcast; latency hides in build)
  St P;
  {
    const float4* pp = (const float4*)(prefb + (size_t)cid*12);
    float4 a = pp[0], bb = pp[1], cc = pp[2];
    P.q = {a.x, a.y, a.z, a.w};
    P.s = {bb.x, bb.y, bb.z};
    P.p = {bb.w, cc.x, cc.y};
    P.T = cc.z; P.pad = 0.0f;
  }

  // build: compressed element states + thread-local aggregate
  float cq[SEQ*3], cs[SEQ*3], cdt[SEQ];
  St run;
  {
    float dtv[SEQ], gy[SEQ*3], acv[SEQ*3], gq[SEQ*4];
    *((float4*)dtv) = *(const float4*)(dtp + gi);
    #pragma unroll
    for (int j = 0; j < 3; ++j) ((float4*)gy)[j]  = ((const float4*)(gyp + gi*3))[j];
    #pragma unroll
    for (int j = 0; j < 3; ++j) ((float4*)acv)[j] = ((const float4*)(acp + gi*3))[j];
    #pragma unroll
    for (int j = 0; j < 4; ++j) ((float4*)gq)[j]  = ((const float4*)(gtp + gi*4))[j];
    #pragma unroll
    for (int i = 0; i < SEQ; ++i) {
      St e = elem_state(dtv[i],
                 {gy[3*i], gy[3*i+1], gy[3*i+2]},
                 {acv[3*i], acv[3*i+1], acv[3*i+2]},
                 {gq[4*i], gq[4*i+1], gq[4*i+2], gq[4*i+3]});
      cq[3*i] = e.q.x; cq[3*i+1] = e.q.y; cq[3*i+2] = e.q.z;
      cs[3*i] = e.s.x; cs[3*i+1] = e.s.y; cs[3*i+2] = e.s.z;
      cdt[i]  = e.T;
      if (i == 0) run = e; else run = combine(run, e);
    }
  }

  // wave inclusive scan of thread aggregates (order-correct), then exclusive
  St incl = run;
  #pragma unroll
  for (int d = 1; d < 64; d <<= 1) {
    St o = shfl_up_st(incl, d);
    if (lane >= d) incl = combine(o, incl);
  }
  {
    St ex = shfl_up_st(incl, 1);
    if (lane > 0) P = combine(P, ex);
  }

  V3 iv = { ivp[b*3+0], ivp[b*3+1], ivp[b*3+2] };
  V3 ip = { ipp[b*3+0], ipp[b*3+1], ipp[b*3+2] };

  const size_t BF = (size_t)B * (size_t)F;
  float4* rot4 = (float4*)out;
  float*  velp = out + BF*4;
  float*  posp = out + BF*7;

  St acc = P;
  float velb[SEQ*3], posb[SEQ*3];
  #pragma unroll
  for (int i = 0; i < SEQ; ++i) {
    St e = recon(cq[3*i], cq[3*i+1], cq[3*i+2],
                 cs[3*i], cs[3*i+1], cs[3*i+2], cdt[i]);
    acc = combine(acc, e);
    rot4[gi + i] = make_float4(acc.q.x, acc.q.y, acc.q.z, acc.q.w);
    velb[3*i+0] = iv.x + acc.s.x;
    velb[3*i+1] = iv.y + acc.s.y;
    velb[3*i+2] = iv.z + acc.s.z;
    posb[3*i+0] = ip.x + iv.x*acc.T + acc.p.x;
    posb[3*i+1] = ip.y + iv.y*acc.T + acc.p.y;
    posb[3*i+2] = ip.z + iv.z*acc.T + acc.p.z;
  }
  #pragma unroll
  for (int j = 0; j < SEQ*3/4; ++j) {
    ((float4*)(velp + gi*3))[j] = ((float4*)velb)[j];
    ((float4*)(posp + gi*3))[j] = ((float4*)posb)[j];
  }
}

} // namespace

extern "C" void kernel_launch(void* const* d_in, const int* in_sizes, int n_in,
                              void* d_out, int out_size, void* d_ws, size_t ws_size,
                              hipStream_t stream)
{
  (void)n_in; (void)out_size; (void)ws_size;

  const float* dtp = (const float*)d_in[0];
  const float* gyp = (const float*)d_in[1];
  const float* acp = (const float*)d_in[2];
  const float* gtp = (const float*)d_in[3];
  const float* irp = (const float*)d_in[4];
  const float* ivp = (const float*)d_in[5];
  const float* ipp = (const float*)d_in[6];
  float* out = (float*)d_out;

  const int B   = in_sizes[4] / 4;    // init_rot has B*4 elements
  const int F   = in_sizes[0] / B;    // dt has B*F elements
  const int cpb = F / WCHUNK;         // 128 for F=32768
  const int nchunk = B * cpb;         // 8192

  St*    aggs  = (St*)d_ws;
  float* prefb = (float*)((char*)d_ws + (size_t)nchunk * sizeof(St));

  k_agg <<<nchunk/4, 256, 0, stream>>>(dtp, gyp, acp, gtp, aggs, F, cpb);
  k_pref<<<B,         64, 0, stream>>>(aggs, irp, prefb, cpb);
  k_emit<<<nchunk/4, 256, 0, stream>>>(dtp, gyp, acp, gtp, prefb, ivp, ipp,
                                       out, F, cpb, B);
}

// Round 11
// 66.438 us; speedup vs baseline: 1.3729x; 1.1480x over previous
//
#include <hip/hip_runtime.h>
#include <math.h>

namespace {

constexpr int SEQ    = 4;
constexpr int WCHUNK = 64 * SEQ;   // 256 elements = one wave's chunk
constexpr int BELEMS = 1024;       // block = 4 waves x 256 elems

// LDS float-index region offsets (each region base is 256B-aligned)
constexpr int GY_F  = 0;           // 3072 floats (12 KB)  gyro  | vel out
constexpr int AC_F  = 3072;        // 3072 floats (12 KB)  acc   | pos out
constexpr int GT_F  = 6144;        // 4096 floats (16 KB)  gt    | rot out
constexpr int LDS_F = 10240;       // 40 KB total

struct V3 { float x, y, z; };
struct Q4 { float x, y, z, w; };
struct St { Q4 q; V3 s; V3 p; float T; float pad; }; // 48 B

__device__ __forceinline__ Q4 qmul(const Q4 a, const Q4 b) {
  Q4 r;
  r.x = a.w*b.x + b.w*a.x + a.y*b.z - a.z*b.y;
  r.y = a.w*b.y + b.w*a.y + a.z*b.x - a.x*b.z;
  r.z = a.w*b.z + b.w*a.z + a.x*b.y - a.y*b.x;
  r.w = a.w*b.w - a.x*b.x - a.y*b.y - a.z*b.z;
  return r;
}

__device__ __forceinline__ V3 qrot(const Q4 q, const V3 v) {
  float tx = q.y*v.z - q.z*v.y + q.w*v.x;
  float ty = q.z*v.x - q.x*v.z + q.w*v.y;
  float tz = q.x*v.y - q.y*v.x + q.w*v.z;
  V3 r;
  r.x = v.x + 2.0f*(q.y*tz - q.z*ty);
  r.y = v.y + 2.0f*(q.z*tx - q.x*tz);
  r.z = v.z + 2.0f*(q.x*ty - q.y*tx);
  return r;
}

__device__ __forceinline__ St combine(const St a, const St b) {
  St r;
  r.q = qmul(a.q, b.q);
  V3 rs = qrot(a.q, b.s);
  r.s.x = a.s.x + rs.x;
  r.s.y = a.s.y + rs.y;
  r.s.z = a.s.z + rs.z;
  V3 rp = qrot(a.q, b.p);
  r.p.x = a.p.x + a.s.x*b.T + rp.x;
  r.p.y = a.p.y + a.s.y*b.T + rp.y;
  r.p.z = a.p.z + a.s.z*b.T + rp.z;
  r.T = a.T + b.T;
  r.pad = 0.0f;
  return r;
}

__device__ __forceinline__ St identity_st() {
  St r;
  r.q = {0.0f, 0.0f, 0.0f, 1.0f};
  r.s = {0.0f, 0.0f, 0.0f};
  r.p = {0.0f, 0.0f, 0.0f};
  r.T = 0.0f; r.pad = 0.0f;
  return r;
}

// θ = |gyro*dt| ≤ ~0.02 here: 2-term Taylor in θ² is fp32-exact. No libm.
__device__ __forceinline__ St elem_state(float dt, V3 w, V3 ac, Q4 gt) {
  float px = w.x*dt, py = w.y*dt, pz = w.z*dt;
  float t2 = px*px + py*py + pz*pz;                        // θ²
  float k  = 0.5f + t2*(-1.0f/48.0f  + t2*(1.0f/3840.0f)); // sin(θ/2)/θ
  float cw = 1.0f + t2*(-0.125f      + t2*(1.0f/384.0f));  // cos(θ/2)
  Q4 dr = { px*k, py*k, pz*k, cw };
  Q4 gi = { -gt.x, -gt.y, -gt.z, gt.w };
  V3 g  = { 0.0f, 0.0f, 9.81007f };
  V3 gr = qrot(gi, g);
  V3 a  = { ac.x - gr.x, ac.y - gr.y, ac.z - gr.z };
  V3 ra = qrot(dr, a);
  St e;
  e.q = dr;
  e.s.x = ra.x*dt; e.s.y = ra.y*dt; e.s.z = ra.z*dt;
  float h = 0.5f*dt;
  e.p.x = e.s.x*h; e.p.y = e.s.y*h; e.p.z = e.s.z*h;
  e.T = dt; e.pad = 0.0f;
  return e;
}

// reconstruct element state from 7 floats (q.w = sqrt(1-|qv|^2): valid since
// |qv| <= ~0.01, w > 0; validated R7/R9/R10, absmax 16-32)
__device__ __forceinline__ St recon(float qx, float qy, float qz,
                                    float sx, float sy, float sz, float dt) {
  St e;
  e.q = { qx, qy, qz, sqrtf(fmaxf(1.0f - qx*qx - qy*qy - qz*qz, 0.0f)) };
  e.s = { sx, sy, sz };
  float h = 0.5f*dt;
  e.p = { sx*h, sy*h, sz*h };
  e.T = dt; e.pad = 0.0f;
  return e;
}

__device__ __forceinline__ St shfl_up_st(const St& v, int d) {
  St r;
  r.q.x = __shfl_up(v.q.x, d); r.q.y = __shfl_up(v.q.y, d);
  r.q.z = __shfl_up(v.q.z, d); r.q.w = __shfl_up(v.q.w, d);
  r.s.x = __shfl_up(v.s.x, d); r.s.y = __shfl_up(v.s.y, d);
  r.s.z = __shfl_up(v.s.z, d);
  r.p.x = __shfl_up(v.p.x, d); r.p.y = __shfl_up(v.p.y, d);
  r.p.z = __shfl_up(v.p.z, d);
  r.T   = __shfl_up(v.T, d);   r.pad = 0.0f;
  return r;
}

__device__ __forceinline__ St shfl_down_st(const St& v, int d) {
  St r;
  r.q.x = __shfl_down(v.q.x, d); r.q.y = __shfl_down(v.q.y, d);
  r.q.z = __shfl_down(v.q.z, d); r.q.w = __shfl_down(v.q.w, d);
  r.s.x = __shfl_down(v.s.x, d); r.s.y = __shfl_down(v.s.y, d);
  r.s.z = __shfl_down(v.s.z, d);
  r.p.x = __shfl_down(v.p.x, d); r.p.y = __shfl_down(v.p.y, d);
  r.p.z = __shfl_down(v.p.z, d);
  r.T   = __shfl_down(v.T, d);   r.pad = 0.0f;
  return r;
}

__device__ __forceinline__ St bcast_st(const St& v, int src) {
  St r;
  r.q.x = __shfl(v.q.x, src); r.q.y = __shfl(v.q.y, src);
  r.q.z = __shfl(v.q.z, src); r.q.w = __shfl(v.q.w, src);
  r.s.x = __shfl(v.s.x, src); r.s.y = __shfl(v.s.y, src);
  r.s.z = __shfl(v.s.z, src);
  r.p.x = __shfl(v.p.x, src); r.p.y = __shfl(v.p.y, src);
  r.p.z = __shfl(v.p.z, src);
  r.T   = __shfl(v.T, src);   r.pad = 0.0f;
  return r;
}

// Swizzled LDS float4 accessor. XOR of byte-addr bits 4-5 with bits 8-9:
// bijective within each 256 B block (region bases are 256B-aligned), keeps
// 16 B alignment, applied identically on write and read sides. Spreads the
// stride-64B patterns (gt read, rot write) from 2 start-banks to 8.
__device__ __forceinline__ float4& L4(float* lds, int fidx) {
  int a = fidx << 2;
  a ^= ((a >> 8) & 3) << 4;
  return *reinterpret_cast<float4*>(reinterpret_cast<char*>(lds) + a);
}

// Kernel 1: per-chunk aggregates, LDS-staged dense loads.
// Block = 4 waves, 4 consecutive chunks (1024 contiguous elems; global elem
// index of chunk cid is simply cid*256 since F = cpb*256).
__global__ __launch_bounds__(256) void k_agg(
    const float* __restrict__ dtp, const float* __restrict__ gyp,
    const float* __restrict__ acp, const float* __restrict__ gtp,
    St* __restrict__ aggs)
{
  __shared__ __align__(16) float lds[LDS_F];
  const int t = threadIdx.x;
  const int lane = t & 63;
  const size_t base = (size_t)blockIdx.x * BELEMS;

  // dense stage: lane-contiguous float4 loads
  const float4* ggy = (const float4*)(gyp + base*3);
  const float4* gac = (const float4*)(acp + base*3);
  const float4* ggt = (const float4*)(gtp + base*4);
  #pragma unroll
  for (int k = 0; k < 3; ++k) L4(lds, GY_F + 4*(t + 256*k)) = ggy[t + 256*k];
  #pragma unroll
  for (int k = 0; k < 3; ++k) L4(lds, AC_F + 4*(t + 256*k)) = gac[t + 256*k];
  #pragma unroll
  for (int k = 0; k < 4; ++k) L4(lds, GT_F + 4*(t + 256*k)) = ggt[t + 256*k];
  float4 dt4 = ((const float4*)(dtp + base))[t];   // dt already ownership-aligned
  __syncthreads();

  float gy[12], ac[12], gq[16];
  #pragma unroll
  for (int j = 0; j < 3; ++j) ((float4*)gy)[j] = L4(lds, GY_F + 12*t + 4*j);
  #pragma unroll
  for (int j = 0; j < 3; ++j) ((float4*)ac)[j] = L4(lds, AC_F + 12*t + 4*j);
  #pragma unroll
  for (int j = 0; j < 4; ++j) ((float4*)gq)[j] = L4(lds, GT_F + 16*t + 4*j);
  const float dtv[4] = {dt4.x, dt4.y, dt4.z, dt4.w};

  St run;
  #pragma unroll
  for (int i = 0; i < SEQ; ++i) {
    St e = elem_state(dtv[i],
               {gy[3*i], gy[3*i+1], gy[3*i+2]},
               {ac[3*i], ac[3*i+1], ac[3*i+2]},
               {gq[4*i], gq[4*i+1], gq[4*i+2], gq[4*i+3]});
    if (i == 0) run = e; else run = combine(run, e);
  }
  // order-preserving halving reduce (lane i merges [i,i+d) with [i+d,i+2d))
  #pragma unroll
  for (int d = 1; d < 64; d <<= 1) run = combine(run, shfl_down_st(run, d));
  if (lane == 0) aggs[blockIdx.x*4 + (t >> 6)] = run;
}

// Kernel 2: exclusive chunk prefixes. One wave per batch row; cpb scanned in
// 64-wide windows with a running carry (cpb = 128 -> 2 windows).
__global__ __launch_bounds__(64) void k_pref(
    const St* __restrict__ aggs, const float* __restrict__ irp,
    float* __restrict__ prefb, int cpb)
{
  const int b = blockIdx.x;
  const int lane = threadIdx.x & 63;

  St carry = identity_st();
  carry.q = { irp[b*4+0], irp[b*4+1], irp[b*4+2], irp[b*4+3] };

  const int nw = (cpb + 63) >> 6;
  for (int w = 0; w < nw; ++w) {
    const int idx = (w << 6) + lane;
    St A = identity_st();
    if (idx < cpb) A = aggs[(size_t)b*cpb + idx];
    #pragma unroll
    for (int d = 1; d < 64; d <<= 1) {
      St o = shfl_up_st(A, d);
      if (lane >= d) A = combine(o, A);
    }
    St ex = shfl_up_st(A, 1);
    St P = (lane == 0) ? carry : combine(carry, ex);
    if (idx < cpb) {
      float4* pp = (float4*)(prefb + ((size_t)b*cpb + idx)*12);
      pp[0] = make_float4(P.q.x, P.q.y, P.q.z, P.q.w);
      pp[1] = make_float4(P.s.x, P.s.y, P.s.z, P.p.x);
      pp[2] = make_float4(P.p.y, P.p.z, P.T, 0.0f);
    }
    carry = combine(carry, bcast_st(A, 63));
  }
}

// Kernel 3: emit. LDS-staged dense loads AND dense stores (outputs restaged
// through the same 40 KB, regions reused: gt->rot, gy->vel, ac->pos).
__global__ __launch_bounds__(256) void k_emit(
    const float* __restrict__ dtp, const float* __restrict__ gyp,
    const float* __restrict__ acp, const float* __restrict__ gtp,
    const float* __restrict__ prefb,
    const float* __restrict__ ivp, const float* __restrict__ ipp,
    float* __restrict__ out, int F, int cpb, int B)
{
  __shared__ __align__(16) float lds[LDS_F];
  const int t = threadIdx.x;
  const int lane = t & 63;
  const int cid  = blockIdx.x*4 + (t >> 6);
  const int b = cid / cpb;
  const size_t base = (size_t)blockIdx.x * BELEMS;

  // per-wave uniform prefix load (issued first; latency hides under staging)
  St P;
  {
    const float4* pp = (const float4*)(prefb + (size_t)cid*12);
    float4 a = pp[0], bb = pp[1], cc = pp[2];
    P.q = {a.x, a.y, a.z, a.w};
    P.s = {bb.x, bb.y, bb.z};
    P.p = {bb.w, cc.x, cc.y};
    P.T = cc.z; P.pad = 0.0f;
  }

  // dense stage-in
  const float4* ggy = (const float4*)(gyp + base*3);
  const float4* gac = (const float4*)(acp + base*3);
  const float4* ggt = (const float4*)(gtp + base*4);
  #pragma unroll
  for (int k = 0; k < 3; ++k) L4(lds, GY_F + 4*(t + 256*k)) = ggy[t + 256*k];
  #pragma unroll
  for (int k = 0; k < 3; ++k) L4(lds, AC_F + 4*(t + 256*k)) = gac[t + 256*k];
  #pragma unroll
  for (int k = 0; k < 4; ++k) L4(lds, GT_F + 4*(t + 256*k)) = ggt[t + 256*k];
  float4 dt4 = ((const float4*)(dtp + base))[t];
  __syncthreads();

  // build: compressed element states + thread-local aggregate
  float cq[SEQ*3], cs[SEQ*3], cdt[SEQ];
  St run;
  {
    float gy[12], ac[12], gq[16];
    #pragma unroll
    for (int j = 0; j < 3; ++j) ((float4*)gy)[j] = L4(lds, GY_F + 12*t + 4*j);
    #pragma unroll
    for (int j = 0; j < 3; ++j) ((float4*)ac)[j] = L4(lds, AC_F + 12*t + 4*j);
    #pragma unroll
    for (int j = 0; j < 4; ++j) ((float4*)gq)[j] = L4(lds, GT_F + 16*t + 4*j);
    const float dtv[4] = {dt4.x, dt4.y, dt4.z, dt4.w};
    #pragma unroll
    for (int i = 0; i < SEQ; ++i) {
      St e = elem_state(dtv[i],
                 {gy[3*i], gy[3*i+1], gy[3*i+2]},
                 {ac[3*i], ac[3*i+1], ac[3*i+2]},
                 {gq[4*i], gq[4*i+1], gq[4*i+2], gq[4*i+3]});
      cq[3*i] = e.q.x; cq[3*i+1] = e.q.y; cq[3*i+2] = e.q.z;
      cs[3*i] = e.s.x; cs[3*i+1] = e.s.y; cs[3*i+2] = e.s.z;
      cdt[i]  = e.T;
      if (i == 0) run = e; else run = combine(run, e);
    }
  }

  // wave inclusive scan of thread aggregates (order-correct), then exclusive
  St incl = run;
  #pragma unroll
  for (int d = 1; d < 64; d <<= 1) {
    St o = shfl_up_st(incl, d);
    if (lane >= d) incl = combine(o, incl);
  }
  {
    St ex = shfl_up_st(incl, 1);
    if (lane > 0) P = combine(P, ex);
  }

  V3 iv = { ivp[b*3+0], ivp[b*3+1], ivp[b*3+2] };
  V3 ip = { ipp[b*3+0], ipp[b*3+1], ipp[b*3+2] };

  __syncthreads();   // all input reads done; safe to overwrite LDS regions

  // emit into LDS (rot->GT region, vel->GY, pos->AC)
  {
    St acc = P;
    float velb[SEQ*3], posb[SEQ*3];
    #pragma unroll
    for (int i = 0; i < SEQ; ++i) {
      St e = recon(cq[3*i], cq[3*i+1], cq[3*i+2],
                   cs[3*i], cs[3*i+1], cs[3*i+2], cdt[i]);
      acc = combine(acc, e);
      L4(lds, GT_F + 4*(4*t + i)) =
          make_float4(acc.q.x, acc.q.y, acc.q.z, acc.q.w);
      velb[3*i+0] = iv.x + acc.s.x;
      velb[3*i+1] = iv.y + acc.s.y;
      velb[3*i+2] = iv.z + acc.s.z;
      posb[3*i+0] = ip.x + iv.x*acc.T + acc.p.x;
      posb[3*i+1] = ip.y + iv.y*acc.T + acc.p.y;
      posb[3*i+2] = ip.z + iv.z*acc.T + acc.p.z;
    }
    #pragma unroll
    for (int j = 0; j < 3; ++j) L4(lds, GY_F + 12*t + 4*j) = ((float4*)velb)[j];
    #pragma unroll
    for (int j = 0; j < 3; ++j) L4(lds, AC_F + 12*t + 4*j) = ((float4*)posb)[j];
  }
  __syncthreads();

  // dense stores
  const size_t BF = (size_t)B * (size_t)F;
  float4* grot = (float4*)out + base;
  float4* gvel = (float4*)(out + BF*4 + base*3);
  float4* gpos = (float4*)(out + BF*7 + base*3);
  #pragma unroll
  for (int k = 0; k < 4; ++k) grot[t + 256*k] = L4(lds, GT_F + 4*(t + 256*k));
  #pragma unroll
  for (int k = 0; k < 3; ++k) gvel[t + 256*k] = L4(lds, GY_F + 4*(t + 256*k));
  #pragma unroll
  for (int k = 0; k < 3; ++k) gpos[t + 256*k] = L4(lds, AC_F + 4*(t + 256*k));
}

} // namespace

extern "C" void kernel_launch(void* const* d_in, const int* in_sizes, int n_in,
                              void* d_out, int out_size, void* d_ws, size_t ws_size,
                              hipStream_t stream)
{
  (void)n_in; (void)out_size; (void)ws_size;

  const float* dtp = (const float*)d_in[0];
  const float* gyp = (const float*)d_in[1];
  const float* acp = (const float*)d_in[2];
  const float* gtp = (const float*)d_in[3];
  const float* irp = (const float*)d_in[4];
  const float* ivp = (const float*)d_in[5];
  const float* ipp = (const float*)d_in[6];
  float* out = (float*)d_out;

  const int B   = in_sizes[4] / 4;    // init_rot has B*4 elements
  const int F   = in_sizes[0] / B;    // dt has B*F elements
  const int cpb = F / WCHUNK;         // 128 for F=32768
  const int nchunk = B * cpb;         // 8192 (multiple of 4)

  St*    aggs  = (St*)d_ws;
  float* prefb = (float*)((char*)d_ws + (size_t)nchunk * sizeof(St));

  k_agg <<<nchunk/4, 256, 0, stream>>>(dtp, gyp, acp, gtp, aggs);
  k_pref<<<B,         64, 0, stream>>>(aggs, irp, prefb, cpb);
  k_emit<<<nchunk/4, 256, 0, stream>>>(dtp, gyp, acp, gtp, prefb, ivp, ipp,
                                       out, F, cpb, B);
}